// Round 12
// baseline (347.404 us; speedup 1.0000x reference)
//
#include <hip/hip_runtime.h>
#include <hip/hip_bf16.h>

#define FDIM 128
#define HDIM 128
#define ADIM 32
#define PCH 128      // rows per pool block
#define BSH 6        // bucket shift: 64 dst nodes per bucket
#define BWD 64
#define CHUNK 8192   // edges per binning block
#define MAXNB 2048   // max buckets supported (N <= 131072)

// Storage permutation for T'/H rows: byte position p holds col c(p).
// p = m15*8 + nt  <->  col = nt*16 + m15 ;  c(p) = ((p&7)<<4) | (p>>3)
#define CP(p) ((((p) & 7) << 4) | ((p) >> 3))

typedef short v8s __attribute__((ext_vector_type(8)));
typedef float v4f __attribute__((ext_vector_type(4)));
typedef float v2f __attribute__((ext_vector_type(2)));

// bf16x2 helpers (bitwise; bf16->fp32 exact, fp32->bf16 RNE)
static __device__ __forceinline__ float bflo(unsigned int u) {
    return __builtin_bit_cast(float, u << 16);
}
static __device__ __forceinline__ float bfhi(unsigned int u) {
    return __builtin_bit_cast(float, u & 0xffff0000u);
}
static __device__ __forceinline__ unsigned int bfpack(float a, float b) {
    unsigned int ua = __builtin_bit_cast(unsigned int, a);
    unsigned int ub = __builtin_bit_cast(unsigned int, b);
    ua += 0x7fffu + ((ua >> 16) & 1u);
    ub += 0x7fffu + ((ub >> 16) & 1u);
    return (ua >> 16) | (ub & 0xffff0000u);
}

// ---------------------------------------------------------------------------
// fp8 e4m3 (OCP) helpers. HW path: gfx950 cvt instructions.
#if defined(__has_builtin) && __has_builtin(__builtin_amdgcn_cvt_pk_f32_fp8) && \
    __has_builtin(__builtin_amdgcn_cvt_pk_fp8_f32)
#define FP8_HW 1
#endif

static __device__ __forceinline__ v2f fp8_dec_lo(unsigned int u) {
#ifdef FP8_HW
    return __builtin_amdgcn_cvt_pk_f32_fp8(u, false);
#else
    v2f r;
    #pragma unroll
    for (int i = 0; i < 2; ++i) {
        unsigned b = (u >> (8 * i)) & 0xffu;
        unsigned s = b >> 7, e = (b >> 3) & 0xfu, m = b & 7u;
        float v = (e == 0) ? (float)m * 0.001953125f
                           : __builtin_bit_cast(float, ((e + 120u) << 23) | (m << 20));
        r[i] = s ? -v : v;
    }
    return r;
#endif
}
static __device__ __forceinline__ v2f fp8_dec_hi(unsigned int u) {
#ifdef FP8_HW
    return __builtin_amdgcn_cvt_pk_f32_fp8(u, true);
#else
    return fp8_dec_lo(u >> 16);
#endif
}

#ifndef FP8_HW
static __device__ __forceinline__ unsigned int fp8_enc1(float x) {
    unsigned s = __builtin_bit_cast(unsigned, x) >> 31;
    float ax = fabsf(x);
    if (ax > 448.f) return (s << 7) | 0x7Eu;
    if (ax < 0.0009765625f) return s << 7;
    int e2 = (int)((__builtin_bit_cast(unsigned, ax) >> 23) & 0xff) - 127;
    int qe = (e2 < -6 ? -6 : e2) - 3;
    float q = __builtin_bit_cast(float, (unsigned)((qe + 127) << 23));
    float r = rintf(ax / q) * q;
    if (r > 448.f) return (s << 7) | 0x7Eu;
    if (r < 0.001953125f) return s << 7;
    unsigned ub = __builtin_bit_cast(unsigned, r);
    int re = (int)((ub >> 23) & 0xff) - 127;
    if (re < -6) {
        unsigned m = (unsigned)rintf(r * 512.f);
        return (s << 7) | m;
    }
    return (s << 7) | ((unsigned)(re + 7) << 3) | ((ub >> 20) & 7u);
}
#endif

// pack 4 floats -> 4 fp8 bytes in one dword (byte i = value i)
static __device__ __forceinline__ unsigned int fp8x4_enc(float a, float b, float c, float d) {
#ifdef FP8_HW
    int p = __builtin_amdgcn_cvt_pk_fp8_f32(a, b, 0, false);
    p = __builtin_amdgcn_cvt_pk_fp8_f32(c, d, p, true);
    return (unsigned int)p;
#else
    return fp8_enc1(a) | (fp8_enc1(b) << 8) | (fp8_enc1(c) << 16) | (fp8_enc1(d) << 24);
#endif
}

// ---------------------------------------------------------------------------
// Per-block LDS bucket histogram (blocks < NBLK) + fused one-off setup work
// (blocks NBLK..NBLK+2): weight/bias prep, graph bounds, pooled zero.
__global__ __launch_bounds__(256) void block_hist_setup(const int* __restrict__ dst,
                                                        int* __restrict__ hist,  // [nblk][NB]
                                                        int E, int NB, int NBLK,
                                                        const float* __restrict__ W1,
                                                        const float* __restrict__ W2,
                                                        const float* __restrict__ b1,
                                                        const float* __restrict__ b2,
                                                        unsigned short* __restrict__ wsw1,
                                                        unsigned short* __restrict__ wsw2,
                                                        float* __restrict__ pb1,
                                                        float* __restrict__ pb2,
                                                        const int* __restrict__ batch,
                                                        int* __restrict__ gstart,
                                                        float* __restrict__ pooled,
                                                        int n, int G) {
    __shared__ int h[MAXNB];
    const int tid = threadIdx.x;
    if (blockIdx.x >= (unsigned)NBLK) {
        const int role = blockIdx.x - NBLK;
        if (role == 0) {
            for (int idx = tid; idx < 16384; idx += 256) {
                int nn = idx >> 7, k = idx & 127;
                wsw1[idx] = (unsigned short)(bfpack(W1[k * 128 + nn], 0.f) & 0xffffu);
                wsw2[idx] = (unsigned short)(bfpack(W2[CP(k) * 128 + nn], 0.f) & 0xffffu);
            }
            if (tid < 128) {
                pb1[tid] = b1[CP(tid)];
                pb2[tid] = b2[CP(tid)];
            }
        } else if (role == 1) {
            if (tid <= G) {
                int lo = 0, hi = n;
                while (lo < hi) { int mid = (lo + hi) >> 1; if (batch[mid] < tid) lo = mid + 1; else hi = mid; }
                gstart[tid] = lo;
            }
        } else {
            for (int i = tid; i < G * 128; i += 256) pooled[i] = 0.f;
        }
        return;
    }
    for (int i = tid; i < NB; i += 256) h[i] = 0;
    __syncthreads();
    const int base = blockIdx.x * CHUNK;
    int lim = base + CHUNK; if (lim > E) lim = E;
    for (int i = base + tid; i < lim; i += 256) atomicAdd(&h[dst[i] >> BSH], 1);
    __syncthreads();
    int* hrow = hist + (size_t)blockIdx.x * NB;
    for (int b = tid; b < NB; b += 256) hrow[b] = h[b];
}

// Exclusive scan over M = NB*NBLK counts in bucket-major order.
// bsum gets RAW per-block totals (consumers scan it themselves in LDS).
__global__ void scanA(const int* __restrict__ hist, int* __restrict__ excl,
                      int* __restrict__ bsum, int M, int NB, int NBLK) {
    __shared__ int tmp[256];
    const int t = threadIdx.x;
    const int idx = blockIdx.x * 2048 + t * 8;
    int v[8], s = 0;
    #pragma unroll
    for (int i = 0; i < 8; ++i) {
        int p = idx + i;
        v[i] = (p < M) ? hist[(size_t)(p % NBLK) * NB + (p / NBLK)] : 0;
        s += v[i];
    }
    tmp[t] = s;
    __syncthreads();
    for (int off = 1; off < 256; off <<= 1) {
        int x = (t >= off) ? tmp[t - off] : 0;
        __syncthreads();
        tmp[t] += x;
        __syncthreads();
    }
    int run = tmp[t] - s;
    #pragma unroll
    for (int i = 0; i < 8; ++i) {
        int p = idx + i;
        if (p < M) excl[p] = run;
        run += v[i];
    }
    if (t == 255) bsum[blockIdx.x] = tmp[255];
}

// In-block exclusive scan of raw bsum (nA <= 256) into sbs[] (LDS).
// Must be called with all 256 threads; leaves sbs = exclusive prefix.
static __device__ __forceinline__ void scan_bsum_lds(const int* __restrict__ bsum,
                                                     int* sbs, int nA, int t) {
    int v = (t < nA) ? bsum[t] : 0;
    sbs[t] = v;
    __syncthreads();
    for (int off = 1; off < 256; off <<= 1) {
        int x = (t >= off) ? sbs[t - off] : 0;
        __syncthreads();
        sbs[t] += x;
        __syncthreads();
    }
    sbs[t] -= v;  // exclusive
    __syncthreads();
}

// Re-read edges; exact LDS cursors from scanned hist (+LDS-scanned bsum);
// write packed edge (src | node-in-bucket<<26) grouped by bucket.
__global__ __launch_bounds__(256) void bucket_scatter(const int* __restrict__ src,
                                                      const int* __restrict__ dst,
                                                      const int* __restrict__ excl,
                                                      const int* __restrict__ bsum,
                                                      unsigned int* __restrict__ packed,
                                                      int E, int NB, int NBLK, int nA) {
    __shared__ int cur[MAXNB];
    __shared__ int sbs[256];
    const int tid = threadIdx.x;
    const int blk = blockIdx.x;
    scan_bsum_lds(bsum, sbs, nA, tid);
    for (int b = tid; b < NB; b += 256) {
        size_t p = (size_t)b * NBLK + blk;
        cur[b] = excl[p] + sbs[p >> 11];
    }
    __syncthreads();
    const int base = blk * CHUNK;
    int lim = base + CHUNK; if (lim > E) lim = E;
    for (int i = base + tid; i < lim; i += 256) {
        int d = dst[i];
        int s = src[i];
        int pos = atomicAdd(&cur[d >> BSH], 1);  // LDS atomic only
        packed[pos] = (unsigned)s | ((unsigned)(d & (BWD - 1)) << 26);
    }
}

// One block per bucket: in-bucket per-node counts -> rowptr + dinv + node-grouped col.
__global__ __launch_bounds__(256) void bucket_to_csr(const unsigned int* __restrict__ packed,
                                                     const int* __restrict__ excl,
                                                     const int* __restrict__ bsum,
                                                     int* __restrict__ rowptr,
                                                     float* __restrict__ dinv,
                                                     int* __restrict__ col,
                                                     int E, int N, int NB, int NBLK, int nA) {
    __shared__ int cnt[BWD];
    __shared__ int offs[BWD];
    __shared__ int sbs[256];
    const int b = blockIdx.x;
    const int tid = threadIdx.x;
    scan_bsum_lds(bsum, sbs, nA, tid);
    size_t p0 = (size_t)b * NBLK;
    const int base = excl[p0] + sbs[p0 >> 11];
    int next;
    if (b + 1 < NB) {
        size_t p1 = (size_t)(b + 1) * NBLK;
        next = excl[p1] + sbs[p1 >> 11];
    } else {
        next = E;
    }
    if (tid < BWD) cnt[tid] = 0;
    __syncthreads();
    for (int i = base + tid; i < next; i += 256) atomicAdd(&cnt[packed[i] >> 26], 1);
    __syncthreads();
    if (tid == 0) {
        int run = 0;
        for (int j = 0; j < BWD; ++j) { offs[j] = run; run += cnt[j]; }
    }
    __syncthreads();
    if (tid < BWD) {
        int node = (b << BSH) + tid;
        if (node < N) {
            rowptr[node] = base + offs[tid];
            dinv[node] = rsqrtf((float)cnt[tid] + 1.0f);
        }
        cnt[tid] = offs[tid];  // reuse as in-bucket cursors
    }
    if (b == NB - 1 && tid == 0) rowptr[N] = E;
    __syncthreads();
    for (int i = base + tid; i < next; i += 256) {
        unsigned int u = packed[i];
        int j = u >> 26;
        int pos = base + atomicAdd(&cnt[j], 1);  // LDS atomic only
        col[pos] = (int)(u & 0x03ffffffu);
    }
}

// ---------------------------------------------------------------------------
// LDS-free MFMA GEMM: Out[r] = fp8((X[r] @ W) * rowscale[r]), cols in P-order.
// Each wave loads its 16 rows' A-fragments directly from global (full-line
// utilization); W fragments register-double-buffered from L1-resident wsw.
// Layouts (m89/m120-verified): A: m=lane&15, k=quad*8+j. B: n=lane&15,
// k=quad*8+j. C/D: col=lane&15, row=quad*4+reg.
template <bool BF16IN>
__global__ __launch_bounds__(256, 4) void gemm_mfma(const void* __restrict__ Xv,
                                                    const unsigned short* __restrict__ wsw,
                                                    const float* __restrict__ rowscale,
                                                    uint2* __restrict__ Out, int n) {
    const int tid = threadIdx.x;
    const int w = tid >> 6;
    const int lane = tid & 63;
    const int q = lane >> 4;
    const int m15 = lane & 15;
    const int rbase = blockIdx.x * 64;

    const int arow = rbase + w * 16 + m15;
    const int srow = (arow < n) ? arow : (n - 1);  // clamped; garbage rows never stored

    // A fragments straight from global
    v8s a[4];
    if (BF16IN) {
        const unsigned short* xr = (const unsigned short*)Xv + (size_t)srow * 128 + q * 8;
        #pragma unroll
        for (int kk = 0; kk < 4; ++kk)
            a[kk] = __builtin_bit_cast(v8s, *(const uint4*)(xr + kk * 32));
    } else {
        const float* xr = (const float*)Xv + (size_t)srow * 128 + q * 8;
        #pragma unroll
        for (int kk = 0; kk < 4; ++kk) {
            float4 v0 = *(const float4*)(xr + kk * 32);
            float4 v1 = *(const float4*)(xr + kk * 32 + 4);
            uint4 p;
            p.x = bfpack(v0.x, v0.y); p.y = bfpack(v0.z, v0.w);
            p.z = bfpack(v1.x, v1.y); p.w = bfpack(v1.z, v1.w);
            a[kk] = __builtin_bit_cast(v8s, p);
        }
    }

    // W fragments: register double-buffer (prefetch nt+1 during nt's MFMAs)
    const v8s* __restrict__ pW = (const v8s*)wsw;  // fragment idx = row*16 + kk*4 + q
    v8s bcur[4], bnxt[4];
    #pragma unroll
    for (int kk = 0; kk < 4; ++kk) bcur[kk] = pW[(size_t)m15 * 16 + kk * 4 + q];

    v4f acc[8];
    #pragma unroll
    for (int nt = 0; nt < 8; ++nt) acc[nt] = (v4f){0.f, 0.f, 0.f, 0.f};

    #pragma unroll
    for (int nt = 0; nt < 8; ++nt) {
        if (nt < 7) {
            #pragma unroll
            for (int kk = 0; kk < 4; ++kk)
                bnxt[kk] = pW[(size_t)((nt + 1) * 16 + m15) * 16 + kk * 4 + q];
        }
        #pragma unroll
        for (int kk = 0; kk < 4; ++kk)
            acc[nt] = __builtin_amdgcn_mfma_f32_16x16x32_bf16(a[kk], bcur[kk], acc[nt], 0, 0, 0);
        #pragma unroll
        for (int kk = 0; kk < 4; ++kk) bcur[kk] = bnxt[kk];
    }

    // epilogue: D row = q*4+reg, col = nt*16+m15 -> P-order bytes p=m15*8+nt
    #pragma unroll
    for (int reg = 0; reg < 4; ++reg) {
        int row = rbase + w * 16 + q * 4 + reg;
        if (row < n) {
            float sc = rowscale[row];
            unsigned int d0 = fp8x4_enc(acc[0][reg] * sc, acc[1][reg] * sc,
                                        acc[2][reg] * sc, acc[3][reg] * sc);
            unsigned int d1 = fp8x4_enc(acc[4][reg] * sc, acc[5][reg] * sc,
                                        acc[6][reg] * sc, acc[7][reg] * sc);
            Out[(size_t)row * 16 + m15] = make_uint2(d0, d1);
        }
    }
}

// ---------------------------------------------------------------------------
// Fused CSR gather + epilogue on pre-scaled fp8 T' (P-ordered rows):
//   h[d] = relu( (sum_{s in in(d)} T'[s] + T'[d]) * dinv[d] + pbias )
// HALF-wave per dst node (32 lanes x 1 dword = 128 B row); cascade unroll
// 16/8/4/1 with int4 col loads (peeled to 4-aligned e) for deep MLP across
// the col->row dependent chain.
__global__ __launch_bounds__(256) void gather_fused(const unsigned int* __restrict__ T32,
                                                    const int* __restrict__ rowptr,
                                                    const int* __restrict__ col,
                                                    const float* __restrict__ dinv,
                                                    const float* __restrict__ pbias,
                                                    uint2* __restrict__ H, int n) {
    const int wave = (blockIdx.x * 256 + threadIdx.x) >> 6;
    const int d = wave * 2 + ((threadIdx.x >> 5) & 1);
    const int hl = threadIdx.x & 31;
    if (d >= n) return;
    int e = rowptr[d];
    const int end = rowptr[d + 1];

    v2f sl0 = {0.f, 0.f}, sh0 = {0.f, 0.f}, sl1 = {0.f, 0.f}, sh1 = {0.f, 0.f};

    // peel to 4-aligned e for int4 col loads
    while ((e & 3) && e < end) {
        unsigned int u = T32[(size_t)col[e] * 32 + hl];
        sl0 += fp8_dec_lo(u); sh0 += fp8_dec_hi(u);
        ++e;
    }
    // 16-deep: 4 int4 col loads, 16 rows in flight
    for (; e + 15 < end; e += 16) {
        int4 q0 = *(const int4*)(col + e);
        int4 q1 = *(const int4*)(col + e + 4);
        int4 q2 = *(const int4*)(col + e + 8);
        int4 q3 = *(const int4*)(col + e + 12);
        unsigned int u0 = T32[(size_t)q0.x * 32 + hl];
        unsigned int u1 = T32[(size_t)q0.y * 32 + hl];
        unsigned int u2 = T32[(size_t)q0.z * 32 + hl];
        unsigned int u3 = T32[(size_t)q0.w * 32 + hl];
        unsigned int u4 = T32[(size_t)q1.x * 32 + hl];
        unsigned int u5 = T32[(size_t)q1.y * 32 + hl];
        unsigned int u6 = T32[(size_t)q1.z * 32 + hl];
        unsigned int u7 = T32[(size_t)q1.w * 32 + hl];
        unsigned int u8 = T32[(size_t)q2.x * 32 + hl];
        unsigned int u9 = T32[(size_t)q2.y * 32 + hl];
        unsigned int ua = T32[(size_t)q2.z * 32 + hl];
        unsigned int ub = T32[(size_t)q2.w * 32 + hl];
        unsigned int uc = T32[(size_t)q3.x * 32 + hl];
        unsigned int ud = T32[(size_t)q3.y * 32 + hl];
        unsigned int ue = T32[(size_t)q3.z * 32 + hl];
        unsigned int uf = T32[(size_t)q3.w * 32 + hl];
        sl0 += fp8_dec_lo(u0); sh0 += fp8_dec_hi(u0);
        sl1 += fp8_dec_lo(u1); sh1 += fp8_dec_hi(u1);
        sl0 += fp8_dec_lo(u2); sh0 += fp8_dec_hi(u2);
        sl1 += fp8_dec_lo(u3); sh1 += fp8_dec_hi(u3);
        sl0 += fp8_dec_lo(u4); sh0 += fp8_dec_hi(u4);
        sl1 += fp8_dec_lo(u5); sh1 += fp8_dec_hi(u5);
        sl0 += fp8_dec_lo(u6); sh0 += fp8_dec_hi(u6);
        sl1 += fp8_dec_lo(u7); sh1 += fp8_dec_hi(u7);
        sl0 += fp8_dec_lo(u8); sh0 += fp8_dec_hi(u8);
        sl1 += fp8_dec_lo(u9); sh1 += fp8_dec_hi(u9);
        sl0 += fp8_dec_lo(ua); sh0 += fp8_dec_hi(ua);
        sl1 += fp8_dec_lo(ub); sh1 += fp8_dec_hi(ub);
        sl0 += fp8_dec_lo(uc); sh0 += fp8_dec_hi(uc);
        sl1 += fp8_dec_lo(ud); sh1 += fp8_dec_hi(ud);
        sl0 += fp8_dec_lo(ue); sh0 += fp8_dec_hi(ue);
        sl1 += fp8_dec_lo(uf); sh1 += fp8_dec_hi(uf);
    }
    // 8-deep
    if (e + 7 < end) {
        int4 q0 = *(const int4*)(col + e);
        int4 q1 = *(const int4*)(col + e + 4);
        unsigned int u0 = T32[(size_t)q0.x * 32 + hl];
        unsigned int u1 = T32[(size_t)q0.y * 32 + hl];
        unsigned int u2 = T32[(size_t)q0.z * 32 + hl];
        unsigned int u3 = T32[(size_t)q0.w * 32 + hl];
        unsigned int u4 = T32[(size_t)q1.x * 32 + hl];
        unsigned int u5 = T32[(size_t)q1.y * 32 + hl];
        unsigned int u6 = T32[(size_t)q1.z * 32 + hl];
        unsigned int u7 = T32[(size_t)q1.w * 32 + hl];
        sl0 += fp8_dec_lo(u0); sh0 += fp8_dec_hi(u0);
        sl1 += fp8_dec_lo(u1); sh1 += fp8_dec_hi(u1);
        sl0 += fp8_dec_lo(u2); sh0 += fp8_dec_hi(u2);
        sl1 += fp8_dec_lo(u3); sh1 += fp8_dec_hi(u3);
        sl0 += fp8_dec_lo(u4); sh0 += fp8_dec_hi(u4);
        sl1 += fp8_dec_lo(u5); sh1 += fp8_dec_hi(u5);
        sl0 += fp8_dec_lo(u6); sh0 += fp8_dec_hi(u6);
        sl1 += fp8_dec_lo(u7); sh1 += fp8_dec_hi(u7);
        e += 8;
    }
    // 4-deep
    if (e + 3 < end) {
        int4 q0 = *(const int4*)(col + e);
        unsigned int u0 = T32[(size_t)q0.x * 32 + hl];
        unsigned int u1 = T32[(size_t)q0.y * 32 + hl];
        unsigned int u2 = T32[(size_t)q0.z * 32 + hl];
        unsigned int u3 = T32[(size_t)q0.w * 32 + hl];
        sl0 += fp8_dec_lo(u0); sh0 += fp8_dec_hi(u0);
        sl1 += fp8_dec_lo(u1); sh1 += fp8_dec_hi(u1);
        sl0 += fp8_dec_lo(u2); sh0 += fp8_dec_hi(u2);
        sl1 += fp8_dec_lo(u3); sh1 += fp8_dec_hi(u3);
        e += 4;
    }
    // residual
    while (e < end) {
        unsigned int u = T32[(size_t)col[e] * 32 + hl];
        sl0 += fp8_dec_lo(u); sh0 += fp8_dec_hi(u);
        ++e;
    }

    // self term
    unsigned int su = T32[(size_t)d * 32 + hl];
    sl0 += fp8_dec_lo(su); sh0 += fp8_dec_hi(su);
    v2f sl = sl0 + sl1, sh = sh0 + sh1;

    const float di = dinv[d];
    const float4 bv = ((const float4*)pbias)[hl];
    float o0 = fmaxf(fmaf(sl.x, di, bv.x), 0.f);
    float o1 = fmaxf(fmaf(sl.y, di, bv.y), 0.f);
    float o2 = fmaxf(fmaf(sh.x, di, bv.z), 0.f);
    float o3 = fmaxf(fmaf(sh.y, di, bv.w), 0.f);
    uint2 o;
    o.x = bfpack(o0, o1);
    o.y = bfpack(o2, o3);
    H[(size_t)d * 32 + hl] = o;
}

// ---------------------------------------------------------------------------
// Parallel partial-sum pool over bf16 h (P-ordered; pooled P-ordered), bf16x2
// vectorized: thread covers 2 cols, 4 row-lanes per block.
__global__ __launch_bounds__(256) void pool_partial(const unsigned int* __restrict__ h2,
                                                    const int* __restrict__ batch,
                                                    float* __restrict__ pooled, int n) {
    const int c = threadIdx.x & 63;       // cols 2c, 2c+1
    const int rl = threadIdx.x >> 6;      // 0..3
    int r = blockIdx.x * PCH + rl;
    int rend = blockIdx.x * PCH + PCH;
    if (rend > n) rend = n;
    v2f acc = {0.f, 0.f};
    int cur = -1;
    for (; r < rend; r += 4) {
        int g = batch[r];
        if (g != cur) {
            if (cur >= 0) {
                atomicAdd(&pooled[(size_t)cur * 128 + 2 * c], acc.x);
                atomicAdd(&pooled[(size_t)cur * 128 + 2 * c + 1], acc.y);
            }
            acc = (v2f){0.f, 0.f};
            cur = g;
        }
        unsigned int u = h2[(size_t)r * 64 + c];
        acc.x += bflo(u);
        acc.y += bfhi(u);
    }
    if (cur >= 0) {
        atomicAdd(&pooled[(size_t)cur * 128 + 2 * c], acc.x);
        atomicAdd(&pooled[(size_t)cur * 128 + 2 * c + 1], acc.y);
    }
}

// ---------------------------------------------------------------------------
// out layout: [G*A action_mean][A std][G value]. pooled is P-ordered ->
// index head weights by c(p).
__global__ void head_kernel(const float* __restrict__ pooled, const int* __restrict__ gstart,
                            const float* __restrict__ Wa, const float* __restrict__ ba,
                            const float* __restrict__ Wv, const float* __restrict__ bv,
                            const float* __restrict__ log_std, float* __restrict__ out, int G) {
    int g = blockIdx.x;
    int t = threadIdx.x;  // 64
    __shared__ float sp[128];
    float inv = 1.0f / fmaxf((float)(gstart[g + 1] - gstart[g]), 1.0f);
    sp[t] = pooled[(size_t)g * 128 + t] * inv;
    sp[t + 64] = pooled[(size_t)g * 128 + 64 + t] * inv;
    __syncthreads();
    if (t < 32) {
        float s = 0.f;
        #pragma unroll 8
        for (int k = 0; k < 128; ++k) s = fmaf(sp[k], Wa[CP(k) * ADIM + t], s);
        out[g * ADIM + t] = s + ba[t];
        if (g == 0) out[G * ADIM + t] = expf(log_std[t]);
    } else if (t == 32) {
        float s = 0.f;
        #pragma unroll 8
        for (int k = 0; k < 128; ++k) s = fmaf(sp[k], Wv[CP(k)], s);
        out[G * ADIM + ADIM + g] = s + bv[0];
    }
}

// ---------------------------------------------------------------------------
extern "C" void kernel_launch(void* const* d_in, const int* in_sizes, int n_in,
                              void* d_out, int out_size, void* d_ws, size_t ws_size,
                              hipStream_t stream) {
    const float* x       = (const float*)d_in[0];
    const int*   ei      = (const int*)d_in[1];
    const int*   batch   = (const int*)d_in[2];
    const float* W1      = (const float*)d_in[3];
    const float* b1      = (const float*)d_in[4];
    const float* W2      = (const float*)d_in[5];
    const float* b2      = (const float*)d_in[6];
    const float* Wa      = (const float*)d_in[7];
    const float* ba      = (const float*)d_in[8];
    const float* Wv      = (const float*)d_in[9];
    const float* bv      = (const float*)d_in[10];
    const float* log_std = (const float*)d_in[11];
    float* out = (float*)d_out;

    const int N = in_sizes[0] / FDIM;
    const int E = in_sizes[1] / 2;
    const int G = (out_size - ADIM) / (ADIM + 1);
    const int NB = (N + BWD - 1) >> BSH;          // buckets (<= MAXNB for N <= 131072)
    const int NBLK = (E + CHUNK - 1) / CHUNK;     // binning blocks
    const int M = NB * NBLK;                      // scan length
    const int nscanA = (M + 2047) / 2048;         // <= 256

    const int* src = ei;
    const int* dst = ei + E;

    auto align = [](size_t v) { return (v + 255) & ~(size_t)255; };
    char* ws = (char*)d_ws;
    size_t off = 0;
    int*   hist   = (int*)(ws + off);   off = align(off + (size_t)M * 4);
    int*   excl   = (int*)(ws + off);   off = align(off + (size_t)M * 4);
    int*   bsum   = (int*)(ws + off);   off = align(off + (size_t)256 * 4);
    int*   rowptr = (int*)(ws + off);   off = align(off + (size_t)(N + 1) * 4);
    int*   gstart = (int*)(ws + off);   off = align(off + (size_t)(G + 1) * 4);
    float* dinv   = (float*)(ws + off); off = align(off + (size_t)N * 4);
    float* pooled = (float*)(ws + off); off = align(off + (size_t)G * HDIM * 4);
    unsigned short* wsw1 = (unsigned short*)(ws + off); off = align(off + (size_t)16384 * 2);
    unsigned short* wsw2 = (unsigned short*)(ws + off); off = align(off + (size_t)16384 * 2);
    float* pb1    = (float*)(ws + off); off = align(off + (size_t)128 * 4);
    float* pb2    = (float*)(ws + off); off = align(off + (size_t)128 * 4);
    unsigned int* packed = (unsigned int*)(ws + off); off = align(off + (size_t)E * 4);
    int*   col    = (int*)(ws + off);   off = align(off + (size_t)E * 4);
    unsigned int* bufA = (unsigned int*)(ws + off); off = align(off + (size_t)N * 32 * 4);  // fp8 N x 128 (P-order)
    unsigned int* bufB = (unsigned int*)(ws + off); off = align(off + (size_t)N * 64 * 4);  // bf16 N x 128 (P-order)
    (void)ws_size;

    const int blkGemm = (N + 63) / 64;
    const int blkGather = (N + 7) / 8;            // half-wave per node, 8 nodes/block
    const int blkPool = (N + PCH - 1) / PCH;

    // ---- binning -> CSR + dinv (no global atomics); setup fused in ----
    block_hist_setup<<<NBLK + 3, 256, 0, stream>>>(dst, hist, E, NB, NBLK,
                                                   W1, W2, b1, b2, wsw1, wsw2, pb1, pb2,
                                                   batch, gstart, pooled, N, G);
    scanA<<<nscanA, 256, 0, stream>>>(hist, excl, bsum, M, NB, NBLK);
    bucket_scatter<<<NBLK, 256, 0, stream>>>(src, dst, excl, bsum, packed, E, NB, NBLK, nscanA);
    bucket_to_csr<<<NB, 256, 0, stream>>>(packed, excl, bsum, rowptr, dinv, col, E, N, NB, NBLK, nscanA);

    // ---- layer 1 (fp32 in, fp8 P-order out) ----
    gemm_mfma<false><<<blkGemm, 256, 0, stream>>>(x, wsw1, dinv, (uint2*)bufA, N);
    gather_fused<<<blkGather, 256, 0, stream>>>(bufA, rowptr, col, dinv, pb1,
                                                (uint2*)bufB, N);

    // ---- layer 2 (bf16 P-order in, fp8 P-order out) ----
    gemm_mfma<true><<<blkGemm, 256, 0, stream>>>(bufB, wsw2, dinv, (uint2*)bufA, N);
    gather_fused<<<blkGather, 256, 0, stream>>>(bufA, rowptr, col, dinv, pb2,
                                                (uint2*)bufB, N);

    // ---- pool + heads ----
    pool_partial<<<blkPool, 256, 0, stream>>>(bufB, batch, pooled, N);
    head_kernel<<<G, 64, 0, stream>>>(pooled, gstart, Wa, ba, Wv, bv, log_std, out, G);
}